// Round 1
// baseline (639.985 us; speedup 1.0000x reference)
//
#include <hip/hip_runtime.h>
#include <hip/hip_bf16.h>
#include <stdint.h>

// Problem constants (B,T,D,H fixed by the reference)
#define B_    4
#define T_    2048
#define D_    1024
#define H_    16
#define HD_   64
#define ROWS_ (B_ * T_)      // 8192
#define NQKV_ (3 * D_)       // 3072

typedef __attribute__((ext_vector_type(8))) short bf16x8;  // 8 bf16 in 4 VGPRs
typedef __attribute__((ext_vector_type(4))) float f32x4;

__device__ __forceinline__ unsigned short f2bf(float f) {
    union { float f; uint32_t u; } v; v.f = f;
    uint32_t u = v.u;
    uint32_t r = (u + 0x7FFFu + ((u >> 16) & 1u)) >> 16;  // RNE
    return (unsigned short)r;
}

// ---------------- fp32 -> bf16 convert (8 elems/thread) ----------------
__global__ void cvt_bf16_kernel(const float* __restrict__ in,
                                unsigned short* __restrict__ out, int n8) {
    int i = blockIdx.x * blockDim.x + threadIdx.x;
    if (i >= n8) return;
    float4 a = ((const float4*)in)[2 * i];
    float4 b = ((const float4*)in)[2 * i + 1];
    union { bf16x8 v; unsigned short s[8]; } o;
    o.s[0] = f2bf(a.x); o.s[1] = f2bf(a.y); o.s[2] = f2bf(a.z); o.s[3] = f2bf(a.w);
    o.s[4] = f2bf(b.x); o.s[5] = f2bf(b.y); o.s[6] = f2bf(b.z); o.s[7] = f2bf(b.w);
    ((bf16x8*)out)[i] = o.v;
}

// ---------------- bf16 MFMA GEMM: C[M,N] = A[M,K] * B[K,N] ----------------
// 64x64 block tile, BK=32, 256 threads = 4 waves (2x2 of 32x32 wave tiles).
// B staged transposed in LDS (Bs[n][k], stride 48 -> 96B rows: 16B-aligned,
// 24-bank shift per row => only 4-way conflicts on frag reads).
template<int OUT_BF16>
__global__ __launch_bounds__(256) void gemm_bf16_kernel(
    const unsigned short* __restrict__ A,
    const unsigned short* __restrict__ Bm,
    void* __restrict__ Cp, int M, int N, int K)
{
    __shared__ __align__(16) unsigned short As[64 * 48];
    __shared__ __align__(16) unsigned short Bs[64 * 48];

    const int t = threadIdx.x;
    const int w = t >> 6, lane = t & 63;
    const int wr = w >> 1, wc = w & 1;
    const int lm = lane & 15, lq = lane >> 4;
    const int m0 = blockIdx.y * 64;
    const int n0 = blockIdx.x * 64;

    f32x4 acc[2][2];
#pragma unroll
    for (int i = 0; i < 2; i++)
#pragma unroll
        for (int j = 0; j < 2; j++) acc[i][j] = (f32x4){0.f, 0.f, 0.f, 0.f};

    const int am = t >> 2, ak = (t & 3) * 8;   // A staging: 64 rows x 32 k
    const int bk = t >> 3, bn = (t & 7) * 8;   // B staging: 32 k x 64 n

    for (int k0 = 0; k0 < K; k0 += 32) {
        __syncthreads();
        bf16x8 av = *(const bf16x8*)&A[(size_t)(m0 + am) * K + k0 + ak];
        bf16x8 bv = *(const bf16x8*)&Bm[(size_t)(k0 + bk) * N + n0 + bn];
        *(bf16x8*)&As[am * 48 + ak] = av;
#pragma unroll
        for (int i = 0; i < 8; i++)
            Bs[(bn + i) * 48 + bk] = (unsigned short)bv[i];  // transpose store
        __syncthreads();

        // A-frag: lane holds A[m=lm][k=lq*8+j] ; B-frag: B[k=lq*8+j][n=lm]
        bf16x8 af0 = *(const bf16x8*)&As[(wr * 32 + 0  + lm) * 48 + lq * 8];
        bf16x8 af1 = *(const bf16x8*)&As[(wr * 32 + 16 + lm) * 48 + lq * 8];
        bf16x8 bf0 = *(const bf16x8*)&Bs[(wc * 32 + 0  + lm) * 48 + lq * 8];
        bf16x8 bf1 = *(const bf16x8*)&Bs[(wc * 32 + 16 + lm) * 48 + lq * 8];
        acc[0][0] = __builtin_amdgcn_mfma_f32_16x16x32_bf16(af0, bf0, acc[0][0], 0, 0, 0);
        acc[0][1] = __builtin_amdgcn_mfma_f32_16x16x32_bf16(af0, bf1, acc[0][1], 0, 0, 0);
        acc[1][0] = __builtin_amdgcn_mfma_f32_16x16x32_bf16(af1, bf0, acc[1][0], 0, 0, 0);
        acc[1][1] = __builtin_amdgcn_mfma_f32_16x16x32_bf16(af1, bf1, acc[1][1], 0, 0, 0);
    }

    // Epilogue. C/D layout: col = lane&15, row = (lane>>4)*4 + reg (m89/m91-verified)
#pragma unroll
    for (int mt = 0; mt < 2; mt++)
#pragma unroll
        for (int nt = 0; nt < 2; nt++)
#pragma unroll
            for (int r = 0; r < 4; r++) {
                int row = m0 + wr * 32 + mt * 16 + lq * 4 + r;
                int col = n0 + wc * 32 + nt * 16 + lm;
                if (OUT_BF16)
                    ((unsigned short*)Cp)[(size_t)row * N + col] = f2bf(acc[mt][nt][r]);
                else
                    ((float*)Cp)[(size_t)row * N + col] = acc[mt][nt][r];
            }
}

// ---------------- fused causal flash attention ----------------
// Block = (b, h, 64 query rows); 4 waves x 16 rows. Key tiles of 32.
// qkv: [8192, 3072] bf16 (q | k | v each 1024 cols, head h at h*64)
// y:   [8192, 1024] bf16
__global__ __launch_bounds__(256) void attn_kernel(
    const unsigned short* __restrict__ qkv, unsigned short* __restrict__ y)
{
    __shared__ __align__(16) unsigned short Vt[64 * 48];     // V^T: [d][k], stride 48
    __shared__ __align__(16) unsigned short Ps[4][16 * 48];  // per-wave P: [m][k]

    const int bh = blockIdx.x;            // 0..63
    const int qt = blockIdx.y;            // 0..31
    const int b = bh >> 4, h = bh & 15;
    const int t = threadIdx.x;
    const int w = t >> 6, lane = t & 63;
    const int lm = lane & 15, lq = lane >> 4;
    const int q0 = qt * 64 + w * 16;      // this wave's query tile

    // Q A-fragments (held for whole kernel): A[m=lm][k=lq*8+j], d-halves 0/32
    const unsigned short* qbase =
        qkv + (size_t)(b * T_ + q0 + lm) * NQKV_ + h * HD_ + lq * 8;
    bf16x8 qf0 = *(const bf16x8*)qbase;
    bf16x8 qf1 = *(const bf16x8*)(qbase + 32);

    f32x4 o[4];
#pragma unroll
    for (int dt = 0; dt < 4; dt++) o[dt] = (f32x4){0.f, 0.f, 0.f, 0.f};
    float mi[4], li[4];
#pragma unroll
    for (int r = 0; r < 4; r++) { mi[r] = -1e30f; li[r] = 0.f; }

    const int vk = t >> 3, vd = (t & 7) * 8;   // V staging decomposition
    const int kend = qt * 64 + 64;

    for (int kt = 0; kt < kend; kt += 32) {
        __syncthreads();  // protect previous Vt reads
        // stage V tile transposed: Vt[d][k]
        bf16x8 vv = *(const bf16x8*)
            &qkv[(size_t)(b * T_ + kt + vk) * NQKV_ + 2 * D_ + h * HD_ + vd];
#pragma unroll
        for (int i = 0; i < 8; i++) Vt[(vd + i) * 48 + vk] = (unsigned short)vv[i];
        __syncthreads();

        // S = Q K^T for 32 keys (two 16-key MFMA n-tiles).
        // B-operand of Q*K^T == A-style load of K rows (verified m118/m120).
        f32x4 s[2];
#pragma unroll
        for (int nt = 0; nt < 2; nt++) {
            const unsigned short* kbase =
                qkv + (size_t)(b * T_ + kt + nt * 16 + lm) * NQKV_ + D_ + h * HD_ + lq * 8;
            bf16x8 kf0 = *(const bf16x8*)kbase;
            bf16x8 kf1 = *(const bf16x8*)(kbase + 32);
            f32x4 a = (f32x4){0.f, 0.f, 0.f, 0.f};
            a = __builtin_amdgcn_mfma_f32_16x16x32_bf16(qf0, kf0, a, 0, 0, 0);
            a = __builtin_amdgcn_mfma_f32_16x16x32_bf16(qf1, kf1, a, 0, 0, 0);
            s[nt] = a;
        }

        // scale + causal mask; C-layout: row=lq*4+r (query), col=lm (key)
        float tmax[4];
#pragma unroll
        for (int r = 0; r < 4; r++) {
            int qi = q0 + lq * 4 + r;
#pragma unroll
            for (int nt = 0; nt < 2; nt++) {
                int kj = kt + nt * 16 + lm;
                float sv = s[nt][r] * 0.125f;
                s[nt][r] = (kj <= qi) ? sv : -1e30f;
            }
            tmax[r] = fmaxf(s[0][r], s[1][r]);
        }
        // row reductions across the 16 lanes holding one row (xor 1,2,4,8)
#pragma unroll
        for (int d = 1; d < 16; d <<= 1)
#pragma unroll
            for (int r = 0; r < 4; r++)
                tmax[r] = fmaxf(tmax[r], __shfl_xor(tmax[r], d, 64));

        float pv[2][4], tsum[4];
#pragma unroll
        for (int r = 0; r < 4; r++) {
            float mnew = fmaxf(mi[r], tmax[r]);
            float alpha = __expf(mi[r] - mnew);
            pv[0][r] = __expf(s[0][r] - mnew);
            pv[1][r] = __expf(s[1][r] - mnew);
            tsum[r] = pv[0][r] + pv[1][r];
            mi[r] = mnew;
            li[r] *= alpha;
#pragma unroll
            for (int dt = 0; dt < 4; dt++) o[dt][r] *= alpha;
        }
#pragma unroll
        for (int d = 1; d < 16; d <<= 1)
#pragma unroll
            for (int r = 0; r < 4; r++)
                tsum[r] += __shfl_xor(tsum[r], d, 64);
#pragma unroll
        for (int r = 0; r < 4; r++) li[r] += tsum[r];

        // P: C-layout -> LDS row-major [m][k] -> read back as A-fragment
        unsigned short* ps = Ps[w];
#pragma unroll
        for (int nt = 0; nt < 2; nt++)
#pragma unroll
            for (int r = 0; r < 4; r++)
                ps[(lq * 4 + r) * 48 + nt * 16 + lm] = f2bf(pv[nt][r]);

        bf16x8 pf = *(const bf16x8*)&ps[lm * 48 + lq * 8];
#pragma unroll
        for (int dt = 0; dt < 4; dt++) {
            bf16x8 vf = *(const bf16x8*)&Vt[(dt * 16 + lm) * 48 + lq * 8];
            o[dt] = __builtin_amdgcn_mfma_f32_16x16x32_bf16(pf, vf, o[dt], 0, 0, 0);
        }
    }

    // normalize + write y (bf16), y row = b*T + q, col = h*64 + d
#pragma unroll
    for (int dt = 0; dt < 4; dt++)
#pragma unroll
        for (int r = 0; r < 4; r++) {
            float val = o[dt][r] / li[r];
            y[(size_t)(b * T_ + q0 + lq * 4 + r) * D_ + h * HD_ + dt * 16 + lm] = f2bf(val);
        }
}

// ---------------- launch ----------------
extern "C" void kernel_launch(void* const* d_in, const int* in_sizes, int n_in,
                              void* d_out, int out_size, void* d_ws, size_t ws_size,
                              hipStream_t stream) {
    const float* x    = (const float*)d_in[0];
    const float* wqkv = (const float*)d_in[1];
    const float* wout = (const float*)d_in[2];
    float* out = (float*)d_out;

    char* ws = (char*)d_ws;
    unsigned short* xb    = (unsigned short*)ws; ws += (size_t)ROWS_ * D_ * 2;    // 16.8 MB
    unsigned short* wqkvb = (unsigned short*)ws; ws += (size_t)D_ * NQKV_ * 2;    //  6.3 MB
    unsigned short* woutb = (unsigned short*)ws; ws += (size_t)D_ * D_ * 2;       //  2.1 MB
    unsigned short* qkvb  = (unsigned short*)ws; ws += (size_t)ROWS_ * NQKV_ * 2; // 50.3 MB
    unsigned short* yb    = (unsigned short*)ws;                                  // 16.8 MB

    cvt_bf16_kernel<<<(ROWS_ * D_ / 8 + 255) / 256, 256, 0, stream>>>(x, xb, ROWS_ * D_ / 8);
    cvt_bf16_kernel<<<(D_ * NQKV_ / 8 + 255) / 256, 256, 0, stream>>>(wqkv, wqkvb, D_ * NQKV_ / 8);
    cvt_bf16_kernel<<<(D_ * D_ / 8 + 255) / 256, 256, 0, stream>>>(wout, woutb, D_ * D_ / 8);

    // QKV projection: [8192,1024] x [1024,3072] -> bf16 qkv
    gemm_bf16_kernel<1><<<dim3(NQKV_ / 64, ROWS_ / 64), 256, 0, stream>>>(
        xb, wqkvb, qkvb, ROWS_, NQKV_, D_);

    // fused causal attention -> y bf16 [8192,1024]
    attn_kernel<<<dim3(B_ * H_, T_ / 64), 256, 0, stream>>>(qkvb, yb);

    // output projection: [8192,1024] x [1024,1024] -> fp32 d_out
    gemm_bf16_kernel<0><<<dim3(D_ / 64, ROWS_ / 64), 256, 0, stream>>>(
        yb, woutb, out, ROWS_, D_, D_);
}

// Round 2
// 362.369 us; speedup vs baseline: 1.7661x; 1.7661x over previous
//
#include <hip/hip_runtime.h>
#include <hip/hip_bf16.h>
#include <stdint.h>

#define B_    4
#define T_    2048
#define D_    1024
#define H_    16
#define HD_   64
#define ROWS_ (B_ * T_)      // 8192
#define NQKV_ (3 * D_)       // 3072

typedef __attribute__((ext_vector_type(8))) short bf16x8;
typedef __attribute__((ext_vector_type(4))) float f32x4;

__device__ __forceinline__ unsigned short f2bf(float f) {
    union { float f; uint32_t u; } v; v.f = f;
    uint32_t u = v.u;
    return (unsigned short)((u + 0x7FFFu + ((u >> 16) & 1u)) >> 16);  // RNE
}

__device__ __forceinline__ void glds16(const unsigned short* g, unsigned short* l) {
    __builtin_amdgcn_global_load_lds(
        (const __attribute__((address_space(1))) void*)g,
        (__attribute__((address_space(3))) void*)l, 16, 0, 0);
}

// ---------------- fp32 -> bf16 convert (plain) ----------------
__global__ void cvt_bf16_kernel(const float* __restrict__ in,
                                unsigned short* __restrict__ out, int n8) {
    int i = blockIdx.x * blockDim.x + threadIdx.x;
    if (i >= n8) return;
    float4 a = ((const float4*)in)[2 * i];
    float4 b = ((const float4*)in)[2 * i + 1];
    union { bf16x8 v; unsigned short s[8]; } o;
    o.s[0] = f2bf(a.x); o.s[1] = f2bf(a.y); o.s[2] = f2bf(a.z); o.s[3] = f2bf(a.w);
    o.s[4] = f2bf(b.x); o.s[5] = f2bf(b.y); o.s[6] = f2bf(b.z); o.s[7] = f2bf(b.w);
    ((bf16x8*)out)[i] = o.v;
}

// ---------------- fp32 [K][N] -> bf16 transposed [N][K] ----------------
// 64x64 tiles via LDS (stride 65 floats to break bank conflicts).
__global__ __launch_bounds__(256) void tcvt_kernel(const float* __restrict__ in,
                                                   unsigned short* __restrict__ out,
                                                   int K, int N) {
    __shared__ float tile[64 * 65];
    const int t = threadIdx.x;
    const int n0 = blockIdx.x * 64, k0 = blockIdx.y * 64;
#pragma unroll
    for (int it = 0; it < 4; ++it) {
        int id = it * 256 + t;
        int r = id >> 4, c = (id & 15) * 4;     // r = k row, c = n col
        float4 v = *(const float4*)&in[(size_t)(k0 + r) * N + n0 + c];
        tile[r * 65 + c + 0] = v.x; tile[r * 65 + c + 1] = v.y;
        tile[r * 65 + c + 2] = v.z; tile[r * 65 + c + 3] = v.w;
    }
    __syncthreads();
#pragma unroll
    for (int it = 0; it < 2; ++it) {
        int id = it * 256 + t;
        int n = id >> 3, kc = (id & 7) * 8;
        union { bf16x8 v; unsigned short s[8]; } o;
#pragma unroll
        for (int i = 0; i < 8; ++i) o.s[i] = f2bf(tile[(kc + i) * 65 + n]);
        *(bf16x8*)&out[(size_t)(n0 + n) * K + k0 + kc] = o.v;
    }
}

// ---------------- m97-style GEMM: C[M,N] = A[M,K] * Bt[N,K]^T ----------------
// 128x128 tile, BK=32, 4 waves (2x2), 4x4 acc/wave, global_load_lds width 16.
// VSPLIT: QKV gemm — cols <2048 go to qk buffer (ldC=2048, bf16); cols >=2048
// are V and are written TRANSPOSED to vt[bh*64+d][2048] (bf16).
template<int OUT_BF16, int VSPLIT>
__global__ __launch_bounds__(256) void gemm128_kernel(
    const unsigned short* __restrict__ A,
    const unsigned short* __restrict__ Bt,
    void* __restrict__ Cp, int M, int K, int ldC,
    unsigned short* __restrict__ vt)
{
    __shared__ __align__(16) unsigned short As[128 * 32];
    __shared__ __align__(16) unsigned short Bs[128 * 32];

    const int t = threadIdx.x, w = t >> 6, lane = t & 63;
    const int wm = w >> 1, wn = w & 1;
    const int lm = lane & 15, lq = lane >> 4;
    const int m0 = blockIdx.y * 128, n0 = blockIdx.x * 128;

    f32x4 acc[4][4];
#pragma unroll
    for (int i = 0; i < 4; i++)
#pragma unroll
        for (int j = 0; j < 4; j++) acc[i][j] = (f32x4){0.f, 0.f, 0.f, 0.f};

    const int id0 = t, id1 = 256 + t;
    const unsigned short* Ap0 = A + (size_t)(m0 + (id0 >> 2)) * K + (id0 & 3) * 8;
    const unsigned short* Ap1 = A + (size_t)(m0 + (id1 >> 2)) * K + (id1 & 3) * 8;
    const unsigned short* Bp0 = Bt + (size_t)(n0 + (id0 >> 2)) * K + (id0 & 3) * 8;
    const unsigned short* Bp1 = Bt + (size_t)(n0 + (id1 >> 2)) * K + (id1 & 3) * 8;

    for (int k0 = 0; k0 < K; k0 += 32) {
        __syncthreads();
        glds16(Ap0 + k0, &As[id0 * 8]);
        glds16(Ap1 + k0, &As[id1 * 8]);
        glds16(Bp0 + k0, &Bs[id0 * 8]);
        glds16(Bp1 + k0, &Bs[id1 * 8]);
        __syncthreads();

        bf16x8 af[4], bfr[4];
#pragma unroll
        for (int mt = 0; mt < 4; mt++)
            af[mt] = *(const bf16x8*)&As[(wm * 64 + mt * 16 + lm) * 32 + lq * 8];
#pragma unroll
        for (int nt = 0; nt < 4; nt++)
            bfr[nt] = *(const bf16x8*)&Bs[(wn * 64 + nt * 16 + lm) * 32 + lq * 8];
#pragma unroll
        for (int mt = 0; mt < 4; mt++)
#pragma unroll
            for (int nt = 0; nt < 4; nt++)
                acc[mt][nt] = __builtin_amdgcn_mfma_f32_16x16x32_bf16(
                    af[mt], bfr[nt], acc[mt][nt], 0, 0, 0);
    }

    // epilogue: C/D layout col = lane&15, row = (lane>>4)*4 + reg
    if (VSPLIT && n0 >= 2048) {
        // V columns -> vt[(b*16+h)*64 + d][t], bh from col, t from row
#pragma unroll
        for (int mt = 0; mt < 4; mt++)
#pragma unroll
            for (int nt = 0; nt < 4; nt++)
#pragma unroll
                for (int r = 0; r < 4; r++) {
                    int row = m0 + wm * 64 + mt * 16 + lq * 4 + r;
                    int col = n0 + wn * 64 + nt * 16 + lm - 2048;   // 0..1023
                    int bb = row >> 11, tt = row & 2047;
                    size_t vi = ((size_t)((bb * 16 + (col >> 6)) * 64 + (col & 63))) * 2048 + tt;
                    vt[vi] = f2bf(acc[mt][nt][r]);
                }
        return;
    }
#pragma unroll
    for (int mt = 0; mt < 4; mt++)
#pragma unroll
        for (int nt = 0; nt < 4; nt++)
#pragma unroll
            for (int r = 0; r < 4; r++) {
                int row = m0 + wm * 64 + mt * 16 + lq * 4 + r;
                int col = n0 + wn * 64 + nt * 16 + lm;
                if (OUT_BF16)
                    ((unsigned short*)Cp)[(size_t)row * ldC + col] = f2bf(acc[mt][nt][r]);
                else
                    ((float*)Cp)[(size_t)row * ldC + col] = acc[mt][nt][r];
            }
}

// ---------------- fused causal flash attention v2 ----------------
// Block = (b,h) x 128 queries; 4 waves x 32 q each; 64-key tiles.
// K staged [key][d] (pad 72), V^T staged [d][key] (pad 72) from global vt.
// qk: [8192][2048] bf16 = Q | K per row. y: [8192][1024] bf16.
__global__ __launch_bounds__(256) void attn2_kernel(
    const unsigned short* __restrict__ qk,
    const unsigned short* __restrict__ vt,
    unsigned short* __restrict__ y)
{
    __shared__ __align__(16) unsigned short Ks[64 * 72];
    __shared__ __align__(16) unsigned short Vs[64 * 72];
    __shared__ __align__(16) unsigned short Ps[4][32 * 72];

    const int bh = blockIdx.x, qt = blockIdx.y;
    const int b = bh >> 4, h = bh & 15;
    const int t = threadIdx.x, w = t >> 6, lane = t & 63;
    const int lm = lane & 15, lq = lane >> 4;
    const int q0 = qt * 128, qw0 = q0 + w * 32;

    // Q fragments: A[m=lm][k=lq*8+j], 2 m-tiles x 2 k-halves
    bf16x8 qf[2][2];
#pragma unroll
    for (int mt = 0; mt < 2; mt++)
#pragma unroll
        for (int kk = 0; kk < 2; kk++)
            qf[mt][kk] = *(const bf16x8*)
                &qk[(size_t)(b * T_ + qw0 + mt * 16 + lm) * 2048 + h * HD_ + kk * 32 + lq * 8];

    f32x4 o[2][4];
#pragma unroll
    for (int mt = 0; mt < 2; mt++)
#pragma unroll
        for (int dt = 0; dt < 4; dt++) o[mt][dt] = (f32x4){0.f, 0.f, 0.f, 0.f};
    float mi[2][4], li[2][4];
#pragma unroll
    for (int mt = 0; mt < 2; mt++)
#pragma unroll
        for (int r = 0; r < 4; r++) { mi[mt][r] = -1e30f; li[mt][r] = 0.f; }

    unsigned short* psw = Ps[w];
    const float SC = 0.18033688f;  // 0.125 * log2(e); softmax done in exp2 domain
    const int kend = q0 + 128;

    for (int kt = 0; kt < kend; kt += 64) {
        __syncthreads();
#pragma unroll
        for (int it = 0; it < 2; ++it) {
            int id = it * 256 + t;
            int rr = id >> 3, cc = (id & 7) * 8;
            *(bf16x8*)&Ks[rr * 72 + cc] = *(const bf16x8*)
                &qk[(size_t)(b * T_ + kt + rr) * 2048 + D_ + h * HD_ + cc];
            *(bf16x8*)&Vs[rr * 72 + cc] = *(const bf16x8*)
                &vt[(size_t)(bh * 64 + rr) * 2048 + kt + cc];
        }
        __syncthreads();
        if (kt >= qw0 + 32) continue;  // fully-masked for this wave

        // S = Q K^T: 16 MFMAs
        f32x4 s[2][4];
#pragma unroll
        for (int mt = 0; mt < 2; mt++)
#pragma unroll
            for (int nt = 0; nt < 4; nt++) s[mt][nt] = (f32x4){0.f, 0.f, 0.f, 0.f};
#pragma unroll
        for (int nt = 0; nt < 4; nt++)
#pragma unroll
            for (int kk = 0; kk < 2; kk++) {
                bf16x8 kf = *(const bf16x8*)&Ks[(nt * 16 + lm) * 72 + kk * 32 + lq * 8];
#pragma unroll
                for (int mt = 0; mt < 2; mt++)
                    s[mt][nt] = __builtin_amdgcn_mfma_f32_16x16x32_bf16(
                        qf[mt][kk], kf, s[mt][nt], 0, 0, 0);
            }

        // scale + causal mask + row max (C-layout: row = lq*4+r, col = lm)
        float tm[2][4];
#pragma unroll
        for (int mt = 0; mt < 2; mt++)
#pragma unroll
            for (int r = 0; r < 4; r++) {
                int qi = qw0 + mt * 16 + lq * 4 + r;
                float mx = -1e30f;
#pragma unroll
                for (int nt = 0; nt < 4; nt++) {
                    int kj = kt + nt * 16 + lm;
                    float sv = s[mt][nt][r] * SC;
                    sv = (kj <= qi) ? sv : -1e30f;
                    s[mt][nt][r] = sv;
                    mx = fmaxf(mx, sv);
                }
                tm[mt][r] = mx;
            }
#pragma unroll
        for (int d = 1; d < 16; d <<= 1)
#pragma unroll
            for (int mt = 0; mt < 2; mt++)
#pragma unroll
                for (int r = 0; r < 4; r++)
                    tm[mt][r] = fmaxf(tm[mt][r], __shfl_xor(tm[mt][r], d, 64));

        float al[2][4], ts[2][4];
#pragma unroll
        for (int mt = 0; mt < 2; mt++)
#pragma unroll
            for (int r = 0; r < 4; r++) {
                float mn = fmaxf(mi[mt][r], tm[mt][r]);
                al[mt][r] = exp2f(mi[mt][r] - mn);
                mi[mt][r] = mn;
                float sum = 0.f;
#pragma unroll
                for (int nt = 0; nt < 4; nt++) {
                    float p = exp2f(s[mt][nt][r] - mn);
                    s[mt][nt][r] = p;
                    sum += p;
                }
                ts[mt][r] = sum;
            }
#pragma unroll
        for (int d = 1; d < 16; d <<= 1)
#pragma unroll
            for (int mt = 0; mt < 2; mt++)
#pragma unroll
                for (int r = 0; r < 4; r++)
                    ts[mt][r] += __shfl_xor(ts[mt][r], d, 64);
#pragma unroll
        for (int mt = 0; mt < 2; mt++)
#pragma unroll
            for (int r = 0; r < 4; r++) {
                li[mt][r] = li[mt][r] * al[mt][r] + ts[mt][r];
#pragma unroll
                for (int dt = 0; dt < 4; dt++) o[mt][dt][r] *= al[mt][r];
            }

        // P: C-layout -> per-wave LDS [m][k] -> A-fragments
#pragma unroll
        for (int mt = 0; mt < 2; mt++)
#pragma unroll
            for (int nt = 0; nt < 4; nt++)
#pragma unroll
                for (int r = 0; r < 4; r++)
                    psw[(mt * 16 + lq * 4 + r) * 72 + nt * 16 + lm] = f2bf(s[mt][nt][r]);

#pragma unroll
        for (int kk = 0; kk < 2; kk++) {
            bf16x8 pf0 = *(const bf16x8*)&psw[(lm) * 72 + kk * 32 + lq * 8];
            bf16x8 pf1 = *(const bf16x8*)&psw[(16 + lm) * 72 + kk * 32 + lq * 8];
#pragma unroll
            for (int dt = 0; dt < 4; dt++) {
                bf16x8 vf = *(const bf16x8*)&Vs[(dt * 16 + lm) * 72 + kk * 32 + lq * 8];
                o[0][dt] = __builtin_amdgcn_mfma_f32_16x16x32_bf16(pf0, vf, o[0][dt], 0, 0, 0);
                o[1][dt] = __builtin_amdgcn_mfma_f32_16x16x32_bf16(pf1, vf, o[1][dt], 0, 0, 0);
            }
        }
    }

#pragma unroll
    for (int mt = 0; mt < 2; mt++)
#pragma unroll
        for (int r = 0; r < 4; r++) {
            float rli = 1.f / li[mt][r];
#pragma unroll
            for (int dt = 0; dt < 4; dt++)
                y[(size_t)(b * T_ + qw0 + mt * 16 + lq * 4 + r) * D_ + h * HD_ + dt * 16 + lm]
                    = f2bf(o[mt][dt][r] * rli);
        }
}

// ---------------- launch ----------------
extern "C" void kernel_launch(void* const* d_in, const int* in_sizes, int n_in,
                              void* d_out, int out_size, void* d_ws, size_t ws_size,
                              hipStream_t stream) {
    const float* x    = (const float*)d_in[0];
    const float* wqkv = (const float*)d_in[1];
    const float* wout = (const float*)d_in[2];
    float* out = (float*)d_out;

    char* ws = (char*)d_ws;
    unsigned short* xb     = (unsigned short*)ws; ws += (size_t)ROWS_ * D_ * 2;     // 16.8 MB
    unsigned short* wqkvbt = (unsigned short*)ws; ws += (size_t)D_ * NQKV_ * 2;     //  6.3 MB [3072][1024]
    unsigned short* woutbt = (unsigned short*)ws; ws += (size_t)D_ * D_ * 2;        //  2.1 MB [1024][1024]
    unsigned short* qkb    = (unsigned short*)ws; ws += (size_t)ROWS_ * 2048 * 2;   // 33.6 MB [8192][2048]
    unsigned short* vtb    = (unsigned short*)ws; ws += (size_t)ROWS_ * D_ * 2;     // 16.8 MB [64*64][2048]
    unsigned short* yb     = (unsigned short*)ws;                                   // 16.8 MB

    cvt_bf16_kernel<<<ROWS_ * D_ / 8 / 256, 256, 0, stream>>>(x, xb, ROWS_ * D_ / 8);
    tcvt_kernel<<<dim3(NQKV_ / 64, D_ / 64), 256, 0, stream>>>(wqkv, wqkvbt, D_, NQKV_);
    tcvt_kernel<<<dim3(D_ / 64, D_ / 64), 256, 0, stream>>>(wout, woutbt, D_, D_);

    // QKV projection: Q,K -> qkb [8192][2048]; V -> vtb transposed [1024-bh*d][2048]
    gemm128_kernel<1, 1><<<dim3(NQKV_ / 128, ROWS_ / 128), 256, 0, stream>>>(
        xb, wqkvbt, qkb, ROWS_, D_, 2048, vtb);

    attn2_kernel<<<dim3(B_ * H_, T_ / 128), 256, 0, stream>>>(qkb, vtb, yb);

    gemm128_kernel<0, 0><<<dim3(D_ / 128, ROWS_ / 128), 256, 0, stream>>>(
        yb, woutbt, out, ROWS_, D_, D_, nullptr);
}

// Round 3
// 274.608 us; speedup vs baseline: 2.3305x; 1.3196x over previous
//
#include <hip/hip_runtime.h>
#include <hip/hip_bf16.h>
#include <stdint.h>

#define B_    4
#define T_    2048
#define D_    1024
#define H_    16
#define HD_   64
#define ROWS_ (B_ * T_)      // 8192
#define NQKV_ (3 * D_)       // 3072

typedef __attribute__((ext_vector_type(8))) short bf16x8;
typedef __attribute__((ext_vector_type(4))) float f32x4;

__device__ __forceinline__ unsigned short f2bf(float f) {
    union { float f; uint32_t u; } v; v.f = f;
    uint32_t u = v.u;
    return (unsigned short)((u + 0x7FFFu + ((u >> 16) & 1u)) >> 16);  // RNE
}

__device__ __forceinline__ void glds16(const unsigned short* g, unsigned short* l) {
    __builtin_amdgcn_global_load_lds(
        (const __attribute__((address_space(1))) void*)g,
        (__attribute__((address_space(3))) void*)l, 16, 0, 0);
}

// ---------------- fp32 -> bf16 convert (plain) ----------------
__global__ void cvt_bf16_kernel(const float* __restrict__ in,
                                unsigned short* __restrict__ out, int n8) {
    int i = blockIdx.x * blockDim.x + threadIdx.x;
    if (i >= n8) return;
    float4 a = ((const float4*)in)[2 * i];
    float4 b = ((const float4*)in)[2 * i + 1];
    union { bf16x8 v; unsigned short s[8]; } o;
    o.s[0] = f2bf(a.x); o.s[1] = f2bf(a.y); o.s[2] = f2bf(a.z); o.s[3] = f2bf(a.w);
    o.s[4] = f2bf(b.x); o.s[5] = f2bf(b.y); o.s[6] = f2bf(b.z); o.s[7] = f2bf(b.w);
    ((bf16x8*)out)[i] = o.v;
}

// ---------------- fp32 [K][N] -> bf16 transposed [N][K] ----------------
// 64x64 tiles via LDS (stride 65 floats). Columns n < ncut scaled by `scale`
// (folds the attention softmax scale into W_q at fp32 precision).
__global__ __launch_bounds__(256) void tcvt_kernel(const float* __restrict__ in,
                                                   unsigned short* __restrict__ out,
                                                   int K, int N, int ncut, float scale) {
    __shared__ float tile[64 * 65];
    const int t = threadIdx.x;
    const int n0 = blockIdx.x * 64, k0 = blockIdx.y * 64;
#pragma unroll
    for (int it = 0; it < 4; ++it) {
        int id = it * 256 + t;
        int r = id >> 4, c = (id & 15) * 4;
        float4 v = *(const float4*)&in[(size_t)(k0 + r) * N + n0 + c];
        tile[r * 65 + c + 0] = v.x; tile[r * 65 + c + 1] = v.y;
        tile[r * 65 + c + 2] = v.z; tile[r * 65 + c + 3] = v.w;
    }
    __syncthreads();
#pragma unroll
    for (int it = 0; it < 2; ++it) {
        int id = it * 256 + t;
        int n = id >> 3, kc = (id & 7) * 8;
        float sc = (n0 + n < ncut) ? scale : 1.0f;
        union { bf16x8 v; unsigned short s[8]; } o;
#pragma unroll
        for (int i = 0; i < 8; ++i) o.s[i] = f2bf(tile[(kc + i) * 65 + n] * sc);
        *(bf16x8*)&out[(size_t)(n0 + n) * K + k0 + kc] = o.v;
    }
}

// ---------------- m97-style GEMM: C[M,N] = A[M,K] * Bt[N,K]^T ----------------
template<int OUT_BF16, int VSPLIT>
__global__ __launch_bounds__(256) void gemm128_kernel(
    const unsigned short* __restrict__ A,
    const unsigned short* __restrict__ Bt,
    void* __restrict__ Cp, int M, int K, int ldC,
    unsigned short* __restrict__ vt)
{
    __shared__ __align__(16) unsigned short As[128 * 32];
    __shared__ __align__(16) unsigned short Bs[128 * 32];

    const int t = threadIdx.x, w = t >> 6, lane = t & 63;
    const int wm = w >> 1, wn = w & 1;
    const int lm = lane & 15, lq = lane >> 4;
    const int m0 = blockIdx.y * 128, n0 = blockIdx.x * 128;

    f32x4 acc[4][4];
#pragma unroll
    for (int i = 0; i < 4; i++)
#pragma unroll
        for (int j = 0; j < 4; j++) acc[i][j] = (f32x4){0.f, 0.f, 0.f, 0.f};

    const int id0 = t, id1 = 256 + t;
    const unsigned short* Ap0 = A + (size_t)(m0 + (id0 >> 2)) * K + (id0 & 3) * 8;
    const unsigned short* Ap1 = A + (size_t)(m0 + (id1 >> 2)) * K + (id1 & 3) * 8;
    const unsigned short* Bp0 = Bt + (size_t)(n0 + (id0 >> 2)) * K + (id0 & 3) * 8;
    const unsigned short* Bp1 = Bt + (size_t)(n0 + (id1 >> 2)) * K + (id1 & 3) * 8;

    for (int k0 = 0; k0 < K; k0 += 32) {
        __syncthreads();
        glds16(Ap0 + k0, &As[id0 * 8]);
        glds16(Ap1 + k0, &As[id1 * 8]);
        glds16(Bp0 + k0, &Bs[id0 * 8]);
        glds16(Bp1 + k0, &Bs[id1 * 8]);
        __syncthreads();

        bf16x8 af[4], bfr[4];
#pragma unroll
        for (int mt = 0; mt < 4; mt++)
            af[mt] = *(const bf16x8*)&As[(wm * 64 + mt * 16 + lm) * 32 + lq * 8];
#pragma unroll
        for (int nt = 0; nt < 4; nt++)
            bfr[nt] = *(const bf16x8*)&Bs[(wn * 64 + nt * 16 + lm) * 32 + lq * 8];
#pragma unroll
        for (int mt = 0; mt < 4; mt++)
#pragma unroll
            for (int nt = 0; nt < 4; nt++)
                acc[mt][nt] = __builtin_amdgcn_mfma_f32_16x16x32_bf16(
                    af[mt], bfr[nt], acc[mt][nt], 0, 0, 0);
    }

    if (VSPLIT && n0 >= 2048) {
#pragma unroll
        for (int mt = 0; mt < 4; mt++)
#pragma unroll
            for (int nt = 0; nt < 4; nt++)
#pragma unroll
                for (int r = 0; r < 4; r++) {
                    int row = m0 + wm * 64 + mt * 16 + lq * 4 + r;
                    int col = n0 + wn * 64 + nt * 16 + lm - 2048;
                    int bb = row >> 11, tt = row & 2047;
                    size_t vi = ((size_t)((bb * 16 + (col >> 6)) * 64 + (col & 63))) * 2048 + tt;
                    vt[vi] = f2bf(acc[mt][nt][r]);
                }
        return;
    }
#pragma unroll
    for (int mt = 0; mt < 4; mt++)
#pragma unroll
        for (int nt = 0; nt < 4; nt++)
#pragma unroll
            for (int r = 0; r < 4; r++) {
                int row = m0 + wm * 64 + mt * 16 + lq * 4 + r;
                int col = n0 + wn * 64 + nt * 16 + lm;
                if (OUT_BF16)
                    ((unsigned short*)Cp)[(size_t)row * ldC + col] = f2bf(acc[mt][nt][r]);
                else
                    ((float*)Cp)[(size_t)row * ldC + col] = acc[mt][nt][r];
            }
}

// ---------------- fused causal flash attention v3 ----------------
// Max-free softmax (scale folded into W_q as 0.125*log2e; p = exp2(s)),
// row-sum via ones-MFMA. Block = (b,h) x pair of query tiles {15-i, i}
// (uniform work 17 key-tiles/block). 4 waves x 32 q; 64-key tiles.
__global__ __launch_bounds__(256) void attn3_kernel(
    const unsigned short* __restrict__ qk,
    const unsigned short* __restrict__ vt,
    unsigned short* __restrict__ y)
{
    __shared__ __align__(16) unsigned short Ks[64 * 72];
    __shared__ __align__(16) unsigned short Vs[64 * 72];
    __shared__ __align__(16) unsigned short Ps[4][32 * 72];

    const int bh = blockIdx.x, pair = blockIdx.y;
    const int b = bh >> 4, h = bh & 15;
    const int t = threadIdx.x, w = t >> 6, lane = t & 63;
    const int lm = lane & 15, lq = lane >> 4;
    unsigned short* psw = Ps[w];

    const bf16x8 onesf = {0x3F80, 0x3F80, 0x3F80, 0x3F80,
                          0x3F80, 0x3F80, 0x3F80, 0x3F80};  // bf16 1.0 x8

    for (int which = 0; which < 2; ++which) {
        const int qt = which ? pair : (15 - pair);   // big tile first
        const int q0 = qt * 128, qw0 = q0 + w * 32;

        bf16x8 qf[2][2];
#pragma unroll
        for (int mt = 0; mt < 2; mt++)
#pragma unroll
            for (int kk = 0; kk < 2; kk++)
                qf[mt][kk] = *(const bf16x8*)
                    &qk[(size_t)(b * T_ + qw0 + mt * 16 + lm) * 2048 + h * HD_ + kk * 32 + lq * 8];

        f32x4 o[2][4], osum[2];
#pragma unroll
        for (int mt = 0; mt < 2; mt++) {
            osum[mt] = (f32x4){0.f, 0.f, 0.f, 0.f};
#pragma unroll
            for (int dt = 0; dt < 4; dt++) o[mt][dt] = (f32x4){0.f, 0.f, 0.f, 0.f};
        }

        const int kend = q0 + 128;
        for (int kt = 0; kt < kend; kt += 64) {
            __syncthreads();
#pragma unroll
            for (int it = 0; it < 2; ++it) {
                int id = it * 256 + t;
                int rr = id >> 3, cc = (id & 7) * 8;
                *(bf16x8*)&Ks[rr * 72 + cc] = *(const bf16x8*)
                    &qk[(size_t)(b * T_ + kt + rr) * 2048 + D_ + h * HD_ + cc];
                *(bf16x8*)&Vs[rr * 72 + cc] = *(const bf16x8*)
                    &vt[(size_t)(bh * 64 + rr) * 2048 + kt + cc];
            }
            __syncthreads();
            if (kt >= qw0 + 32) continue;  // fully masked for this wave

            // S = Q K^T (16 MFMAs); s is already in exp2 domain
            f32x4 s[2][4];
#pragma unroll
            for (int mt = 0; mt < 2; mt++)
#pragma unroll
                for (int nt = 0; nt < 4; nt++) s[mt][nt] = (f32x4){0.f, 0.f, 0.f, 0.f};
#pragma unroll
            for (int nt = 0; nt < 4; nt++)
#pragma unroll
                for (int kk = 0; kk < 2; kk++) {
                    bf16x8 kf = *(const bf16x8*)&Ks[(nt * 16 + lm) * 72 + kk * 32 + lq * 8];
#pragma unroll
                    for (int mt = 0; mt < 2; mt++)
                        s[mt][nt] = __builtin_amdgcn_mfma_f32_16x16x32_bf16(
                            qf[mt][kk], kf, s[mt][nt], 0, 0, 0);
                }

            // p = exp2(s) (+ causal mask only on diagonal tiles) -> bf16 -> Ps
            const bool need_mask = (kt + 64 > qw0);
            if (need_mask) {
#pragma unroll
                for (int mt = 0; mt < 2; mt++)
#pragma unroll
                    for (int nt = 0; nt < 4; nt++)
#pragma unroll
                        for (int r = 0; r < 4; r++) {
                            int qi = qw0 + mt * 16 + lq * 4 + r;
                            int kj = kt + nt * 16 + lm;
                            float p = (kj <= qi) ? exp2f(s[mt][nt][r]) : 0.f;
                            psw[(mt * 16 + lq * 4 + r) * 72 + nt * 16 + lm] = f2bf(p);
                        }
            } else {
#pragma unroll
                for (int mt = 0; mt < 2; mt++)
#pragma unroll
                    for (int nt = 0; nt < 4; nt++)
#pragma unroll
                        for (int r = 0; r < 4; r++)
                            psw[(mt * 16 + lq * 4 + r) * 72 + nt * 16 + lm]
                                = f2bf(exp2f(s[mt][nt][r]));
            }

            // PV (16 MFMAs) + row-sum via ones-MFMA (4 MFMAs)
#pragma unroll
            for (int kk = 0; kk < 2; kk++) {
                bf16x8 pf0 = *(const bf16x8*)&psw[(lm) * 72 + kk * 32 + lq * 8];
                bf16x8 pf1 = *(const bf16x8*)&psw[(16 + lm) * 72 + kk * 32 + lq * 8];
                osum[0] = __builtin_amdgcn_mfma_f32_16x16x32_bf16(pf0, onesf, osum[0], 0, 0, 0);
                osum[1] = __builtin_amdgcn_mfma_f32_16x16x32_bf16(pf1, onesf, osum[1], 0, 0, 0);
#pragma unroll
                for (int dt = 0; dt < 4; dt++) {
                    bf16x8 vf = *(const bf16x8*)&Vs[(dt * 16 + lm) * 72 + kk * 32 + lq * 8];
                    o[0][dt] = __builtin_amdgcn_mfma_f32_16x16x32_bf16(pf0, vf, o[0][dt], 0, 0, 0);
                    o[1][dt] = __builtin_amdgcn_mfma_f32_16x16x32_bf16(pf1, vf, o[1][dt], 0, 0, 0);
                }
            }
        }

#pragma unroll
        for (int mt = 0; mt < 2; mt++)
#pragma unroll
            for (int r = 0; r < 4; r++) {
                float rli = 1.f / osum[mt][r];
#pragma unroll
                for (int dt = 0; dt < 4; dt++)
                    y[(size_t)(b * T_ + qw0 + mt * 16 + lq * 4 + r) * D_ + h * HD_ + dt * 16 + lm]
                        = f2bf(o[mt][dt][r] * rli);
            }
    }
}

// ---------------- launch ----------------
extern "C" void kernel_launch(void* const* d_in, const int* in_sizes, int n_in,
                              void* d_out, int out_size, void* d_ws, size_t ws_size,
                              hipStream_t stream) {
    const float* x    = (const float*)d_in[0];
    const float* wqkv = (const float*)d_in[1];
    const float* wout = (const float*)d_in[2];
    float* out = (float*)d_out;

    char* ws = (char*)d_ws;
    unsigned short* xb     = (unsigned short*)ws; ws += (size_t)ROWS_ * D_ * 2;
    unsigned short* wqkvbt = (unsigned short*)ws; ws += (size_t)D_ * NQKV_ * 2;
    unsigned short* woutbt = (unsigned short*)ws; ws += (size_t)D_ * D_ * 2;
    unsigned short* qkb    = (unsigned short*)ws; ws += (size_t)ROWS_ * 2048 * 2;
    unsigned short* vtb    = (unsigned short*)ws; ws += (size_t)ROWS_ * D_ * 2;
    unsigned short* yb     = (unsigned short*)ws;

    const float SC = 0.18033688011112042f;  // 0.125 * log2(e): softmax in exp2 domain

    cvt_bf16_kernel<<<ROWS_ * D_ / 8 / 256, 256, 0, stream>>>(x, xb, ROWS_ * D_ / 8);
    tcvt_kernel<<<dim3(NQKV_ / 64, D_ / 64), 256, 0, stream>>>(wqkv, wqkvbt, D_, NQKV_, D_, SC);
    tcvt_kernel<<<dim3(D_ / 64, D_ / 64), 256, 0, stream>>>(wout, woutbt, D_, D_, 0, 1.0f);

    gemm128_kernel<1, 1><<<dim3(NQKV_ / 128, ROWS_ / 128), 256, 0, stream>>>(
        xb, wqkvbt, qkb, ROWS_, D_, 2048, vtb);

    attn3_kernel<<<dim3(B_ * H_, 8), 256, 0, stream>>>(qkb, vtb, yb);

    gemm128_kernel<0, 0><<<dim3(D_ / 128, ROWS_ / 128), 256, 0, stream>>>(
        yb, woutbt, out, ROWS_, D_, D_, nullptr);
}

// Round 4
// 260.614 us; speedup vs baseline: 2.4557x; 1.0537x over previous
//
#include <hip/hip_runtime.h>
#include <hip/hip_bf16.h>
#include <stdint.h>

#define B_    4
#define T_    2048
#define D_    1024
#define H_    16
#define HD_   64
#define ROWS_ (B_ * T_)      // 8192
#define NQKV_ (3 * D_)       // 3072

typedef __attribute__((ext_vector_type(8))) short bf16x8;
typedef __attribute__((ext_vector_type(4))) float f32x4;

__device__ __forceinline__ unsigned short f2bf(float f) {
    union { float f; uint32_t u; } v; v.f = f;
    uint32_t u = v.u;
    return (unsigned short)((u + 0x7FFFu + ((u >> 16) & 1u)) >> 16);  // RNE
}

// RTZ pack of two floats to bf16x2 (lo = a). Used only for P (softmax
// self-normalizes: osum uses the same bf16 P, so the bias cancels).
__device__ __forceinline__ uint32_t pack2_rtz(float a, float b) {
    union { float f; uint32_t u; } x, y; x.f = a; y.f = b;
    return (x.u >> 16) | (y.u & 0xFFFF0000u);
}

__device__ __forceinline__ void glds16(const unsigned short* g, unsigned short* l) {
    __builtin_amdgcn_global_load_lds(
        (const __attribute__((address_space(1))) void*)g,
        (__attribute__((address_space(3))) void*)l, 16, 0, 0);
}

// ---------------- fp32 -> bf16 convert (plain) ----------------
__global__ void cvt_bf16_kernel(const float* __restrict__ in,
                                unsigned short* __restrict__ out, int n8) {
    int i = blockIdx.x * blockDim.x + threadIdx.x;
    if (i >= n8) return;
    float4 a = ((const float4*)in)[2 * i];
    float4 b = ((const float4*)in)[2 * i + 1];
    union { bf16x8 v; unsigned short s[8]; } o;
    o.s[0] = f2bf(a.x); o.s[1] = f2bf(a.y); o.s[2] = f2bf(a.z); o.s[3] = f2bf(a.w);
    o.s[4] = f2bf(b.x); o.s[5] = f2bf(b.y); o.s[6] = f2bf(b.z); o.s[7] = f2bf(b.w);
    ((bf16x8*)out)[i] = o.v;
}

// ---------------- fp32 [K][N] -> bf16 transposed [N][K] ----------------
__global__ __launch_bounds__(256) void tcvt_kernel(const float* __restrict__ in,
                                                   unsigned short* __restrict__ out,
                                                   int K, int N, int ncut, float scale) {
    __shared__ float tile[64 * 65];
    const int t = threadIdx.x;
    const int n0 = blockIdx.x * 64, k0 = blockIdx.y * 64;
#pragma unroll
    for (int it = 0; it < 4; ++it) {
        int id = it * 256 + t;
        int r = id >> 4, c = (id & 15) * 4;
        float4 v = *(const float4*)&in[(size_t)(k0 + r) * N + n0 + c];
        tile[r * 65 + c + 0] = v.x; tile[r * 65 + c + 1] = v.y;
        tile[r * 65 + c + 2] = v.z; tile[r * 65 + c + 3] = v.w;
    }
    __syncthreads();
#pragma unroll
    for (int it = 0; it < 2; ++it) {
        int id = it * 256 + t;
        int n = id >> 3, kc = (id & 7) * 8;
        float sc = (n0 + n < ncut) ? scale : 1.0f;
        union { bf16x8 v; unsigned short s[8]; } o;
#pragma unroll
        for (int i = 0; i < 8; ++i) o.s[i] = f2bf(tile[(kc + i) * 65 + n] * sc);
        *(bf16x8*)&out[(size_t)(n0 + n) * K + k0 + kc] = o.v;
    }
}

// ---------------- m97-style GEMM: C[M,N] = A[M,K] * Bt[N,K]^T ----------------
template<int OUT_BF16, int VSPLIT>
__global__ __launch_bounds__(256) void gemm128_kernel(
    const unsigned short* __restrict__ A,
    const unsigned short* __restrict__ Bt,
    void* __restrict__ Cp, int M, int K, int ldC,
    unsigned short* __restrict__ vt)
{
    __shared__ __align__(16) unsigned short As[128 * 32];
    __shared__ __align__(16) unsigned short Bs[128 * 32];

    const int t = threadIdx.x, w = t >> 6, lane = t & 63;
    const int wm = w >> 1, wn = w & 1;
    const int lm = lane & 15, lq = lane >> 4;
    const int m0 = blockIdx.y * 128, n0 = blockIdx.x * 128;

    f32x4 acc[4][4];
#pragma unroll
    for (int i = 0; i < 4; i++)
#pragma unroll
        for (int j = 0; j < 4; j++) acc[i][j] = (f32x4){0.f, 0.f, 0.f, 0.f};

    const int id0 = t, id1 = 256 + t;
    const unsigned short* Ap0 = A + (size_t)(m0 + (id0 >> 2)) * K + (id0 & 3) * 8;
    const unsigned short* Ap1 = A + (size_t)(m0 + (id1 >> 2)) * K + (id1 & 3) * 8;
    const unsigned short* Bp0 = Bt + (size_t)(n0 + (id0 >> 2)) * K + (id0 & 3) * 8;
    const unsigned short* Bp1 = Bt + (size_t)(n0 + (id1 >> 2)) * K + (id1 & 3) * 8;

    for (int k0 = 0; k0 < K; k0 += 32) {
        __syncthreads();
        glds16(Ap0 + k0, &As[id0 * 8]);
        glds16(Ap1 + k0, &As[id1 * 8]);
        glds16(Bp0 + k0, &Bs[id0 * 8]);
        glds16(Bp1 + k0, &Bs[id1 * 8]);
        __syncthreads();

        bf16x8 af[4], bfr[4];
#pragma unroll
        for (int mt = 0; mt < 4; mt++)
            af[mt] = *(const bf16x8*)&As[(wm * 64 + mt * 16 + lm) * 32 + lq * 8];
#pragma unroll
        for (int nt = 0; nt < 4; nt++)
            bfr[nt] = *(const bf16x8*)&Bs[(wn * 64 + nt * 16 + lm) * 32 + lq * 8];
#pragma unroll
        for (int mt = 0; mt < 4; mt++)
#pragma unroll
            for (int nt = 0; nt < 4; nt++)
                acc[mt][nt] = __builtin_amdgcn_mfma_f32_16x16x32_bf16(
                    af[mt], bfr[nt], acc[mt][nt], 0, 0, 0);
    }

    if (VSPLIT && n0 >= 2048) {
        // V columns -> vt[(b*16+h)*64 + d][t]; r=0..3 are contiguous in tt
        // -> one b64 store per (mt,nt)
#pragma unroll
        for (int mt = 0; mt < 4; mt++)
#pragma unroll
            for (int nt = 0; nt < 4; nt++) {
                int row0 = m0 + wm * 64 + mt * 16 + lq * 4;
                int col  = n0 + wn * 64 + nt * 16 + lm - 2048;
                int bb = row0 >> 11, tt = row0 & 2047;
                size_t vi = ((size_t)((bb * 16 + (col >> 6)) * 64 + (col & 63))) * 2048 + tt;
                uint2 pk;
                pk.x = (uint32_t)f2bf(acc[mt][nt][0]) | ((uint32_t)f2bf(acc[mt][nt][1]) << 16);
                pk.y = (uint32_t)f2bf(acc[mt][nt][2]) | ((uint32_t)f2bf(acc[mt][nt][3]) << 16);
                *(uint2*)&vt[vi] = pk;
            }
        return;
    }
#pragma unroll
    for (int mt = 0; mt < 4; mt++)
#pragma unroll
        for (int nt = 0; nt < 4; nt++)
#pragma unroll
            for (int r = 0; r < 4; r++) {
                int row = m0 + wm * 64 + mt * 16 + lq * 4 + r;
                int col = n0 + wn * 64 + nt * 16 + lm;
                if (OUT_BF16)
                    ((unsigned short*)Cp)[(size_t)row * ldC + col] = f2bf(acc[mt][nt][r]);
                else
                    ((float*)Cp)[(size_t)row * ldC + col] = acc[mt][nt][r];
            }
}

// ---------------- fused causal flash attention v4 ----------------
// Max-free softmax + S^T operand-swap (packed b64 P stores) + register
// prefetch of next K/V tile. Block = (b,h) x qt pair {15-i, i}.
__global__ __launch_bounds__(256) void attn4_kernel(
    const unsigned short* __restrict__ qk,
    const unsigned short* __restrict__ vt,
    unsigned short* __restrict__ y)
{
    __shared__ __align__(16) unsigned short Ks[64 * 72];
    __shared__ __align__(16) unsigned short Vs[64 * 72];
    __shared__ __align__(16) unsigned short Ps[4][32 * 72];

    const int bh = blockIdx.x, pair = blockIdx.y;
    const int b = bh >> 4, h = bh & 15;
    const int t = threadIdx.x, w = t >> 6, lane = t & 63;
    const int lm = lane & 15, lq = lane >> 4;
    unsigned short* psw = Ps[w];

    // staging decomposition: two (row, col8) slots per thread
    const int r0 = t >> 3,           c0 = (t & 7) * 8;
    const int r1 = (256 + t) >> 3,   c1 = (t & 7) * 8;
    const unsigned short* kgb = qk + (size_t)(b * T_) * 2048 + D_ + h * HD_;
    const unsigned short* vgb = vt + (size_t)(bh * 64) * 2048;

    const bf16x8 onesf = {0x3F80, 0x3F80, 0x3F80, 0x3F80,
                          0x3F80, 0x3F80, 0x3F80, 0x3F80};  // bf16 1.0 x8

    for (int which = 0; which < 2; ++which) {
        const int qt = which ? pair : (15 - pair);   // big tile first
        const int q0 = qt * 128, qw0 = q0 + w * 32;

        // Q fragments (B-operand): lane holds Q[q=lm][d=lq*8+j]
        bf16x8 qf[2][2];
#pragma unroll
        for (int mt = 0; mt < 2; mt++)
#pragma unroll
            for (int kk = 0; kk < 2; kk++)
                qf[mt][kk] = *(const bf16x8*)
                    &qk[(size_t)(b * T_ + qw0 + mt * 16 + lm) * 2048 + h * HD_ + kk * 32 + lq * 8];

        f32x4 o[2][4], osum[2];
#pragma unroll
        for (int mt = 0; mt < 2; mt++) {
            osum[mt] = (f32x4){0.f, 0.f, 0.f, 0.f};
#pragma unroll
            for (int dt = 0; dt < 4; dt++) o[mt][dt] = (f32x4){0.f, 0.f, 0.f, 0.f};
        }

        const int kend = q0 + 128;

        // prefetch tile 0 into registers
        bf16x8 ka = *(const bf16x8*)&kgb[(size_t)(0 + r0) * 2048 + c0];
        bf16x8 kb = *(const bf16x8*)&kgb[(size_t)(0 + r1) * 2048 + c1];
        bf16x8 va = *(const bf16x8*)&vgb[(size_t)r0 * 2048 + 0 + c0];
        bf16x8 vb = *(const bf16x8*)&vgb[(size_t)r1 * 2048 + 0 + c1];

        for (int kt = 0; kt < kend; kt += 64) {
            __syncthreads();               // previous tile's compute done
            *(bf16x8*)&Ks[r0 * 72 + c0] = ka;
            *(bf16x8*)&Ks[r1 * 72 + c1] = kb;
            *(bf16x8*)&Vs[r0 * 72 + c0] = va;
            *(bf16x8*)&Vs[r1 * 72 + c1] = vb;
            // prefetch next tile (redundant reload of same tile on last iter)
            int ktn = (kt + 64 < kend) ? kt + 64 : kt;
            ka = *(const bf16x8*)&kgb[(size_t)(ktn + r0) * 2048 + c0];
            kb = *(const bf16x8*)&kgb[(size_t)(ktn + r1) * 2048 + c1];
            va = *(const bf16x8*)&vgb[(size_t)r0 * 2048 + ktn + c0];
            vb = *(const bf16x8*)&vgb[(size_t)r1 * 2048 + ktn + c1];
            __syncthreads();
            if (kt >= qw0 + 32) continue;  // fully masked for this wave

            // S^T = K Q^T: lane holds (row=key=lq*4+r, col=query=lm)
            f32x4 st[4][2];
#pragma unroll
            for (int nt = 0; nt < 4; nt++)
#pragma unroll
                for (int mt = 0; mt < 2; mt++) st[nt][mt] = (f32x4){0.f, 0.f, 0.f, 0.f};
#pragma unroll
            for (int nt = 0; nt < 4; nt++)
#pragma unroll
                for (int kk = 0; kk < 2; kk++) {
                    bf16x8 kf = *(const bf16x8*)&Ks[(nt * 16 + lm) * 72 + kk * 32 + lq * 8];
#pragma unroll
                    for (int mt = 0; mt < 2; mt++)
                        st[nt][mt] = __builtin_amdgcn_mfma_f32_16x16x32_bf16(
                            kf, qf[mt][kk], st[nt][mt], 0, 0, 0);
                }

            // p = exp2(s) (mask only diagonal tiles), pack 4 -> b64 store
            const bool diag = (kt + 64 > qw0);
#pragma unroll
            for (int mt = 0; mt < 2; mt++) {
                const int qi = qw0 + mt * 16 + lm;
#pragma unroll
                for (int nt = 0; nt < 4; nt++) {
                    float p[4];
                    if (diag) {
                        const int kj0 = kt + nt * 16 + lq * 4;
#pragma unroll
                        for (int r = 0; r < 4; r++)
                            p[r] = (kj0 + r <= qi)
                                 ? __builtin_amdgcn_exp2f(st[nt][mt][r]) : 0.f;
                    } else {
#pragma unroll
                        for (int r = 0; r < 4; r++)
                            p[r] = __builtin_amdgcn_exp2f(st[nt][mt][r]);
                    }
                    uint2 pk;
                    pk.x = pack2_rtz(p[0], p[1]);
                    pk.y = pack2_rtz(p[2], p[3]);
                    *(uint2*)&psw[(mt * 16 + lm) * 72 + nt * 16 + lq * 4] = pk;
                }
            }

            // PV (16 MFMAs) + row-sum via ones-MFMA (4 MFMAs)
#pragma unroll
            for (int kk = 0; kk < 2; kk++) {
                bf16x8 pf0 = *(const bf16x8*)&psw[(lm) * 72 + kk * 32 + lq * 8];
                bf16x8 pf1 = *(const bf16x8*)&psw[(16 + lm) * 72 + kk * 32 + lq * 8];
                osum[0] = __builtin_amdgcn_mfma_f32_16x16x32_bf16(pf0, onesf, osum[0], 0, 0, 0);
                osum[1] = __builtin_amdgcn_mfma_f32_16x16x32_bf16(pf1, onesf, osum[1], 0, 0, 0);
#pragma unroll
                for (int dt = 0; dt < 4; dt++) {
                    bf16x8 vf = *(const bf16x8*)&Vs[(dt * 16 + lm) * 72 + kk * 32 + lq * 8];
                    o[0][dt] = __builtin_amdgcn_mfma_f32_16x16x32_bf16(pf0, vf, o[0][dt], 0, 0, 0);
                    o[1][dt] = __builtin_amdgcn_mfma_f32_16x16x32_bf16(pf1, vf, o[1][dt], 0, 0, 0);
                }
            }
        }

#pragma unroll
        for (int mt = 0; mt < 2; mt++)
#pragma unroll
            for (int r = 0; r < 4; r++) {
                float rli = 1.f / osum[mt][r];
#pragma unroll
                for (int dt = 0; dt < 4; dt++)
                    y[(size_t)(b * T_ + qw0 + mt * 16 + lq * 4 + r) * D_ + h * HD_ + dt * 16 + lm]
                        = f2bf(o[mt][dt][r] * rli);
            }
    }
}

// ---------------- launch ----------------
extern "C" void kernel_launch(void* const* d_in, const int* in_sizes, int n_in,
                              void* d_out, int out_size, void* d_ws, size_t ws_size,
                              hipStream_t stream) {
    const float* x    = (const float*)d_in[0];
    const float* wqkv = (const float*)d_in[1];
    const float* wout = (const float*)d_in[2];
    float* out = (float*)d_out;

    char* ws = (char*)d_ws;
    unsigned short* xb     = (unsigned short*)ws; ws += (size_t)ROWS_ * D_ * 2;
    unsigned short* wqkvbt = (unsigned short*)ws; ws += (size_t)D_ * NQKV_ * 2;
    unsigned short* woutbt = (unsigned short*)ws; ws += (size_t)D_ * D_ * 2;
    unsigned short* qkb    = (unsigned short*)ws; ws += (size_t)ROWS_ * 2048 * 2;
    unsigned short* vtb    = (unsigned short*)ws; ws += (size_t)ROWS_ * D_ * 2;
    unsigned short* yb     = (unsigned short*)ws;

    const float SC = 0.18033688011112042f;  // 0.125 * log2(e): softmax in exp2 domain

    cvt_bf16_kernel<<<ROWS_ * D_ / 8 / 256, 256, 0, stream>>>(x, xb, ROWS_ * D_ / 8);
    tcvt_kernel<<<dim3(NQKV_ / 64, D_ / 64), 256, 0, stream>>>(wqkv, wqkvbt, D_, NQKV_, D_, SC);
    tcvt_kernel<<<dim3(D_ / 64, D_ / 64), 256, 0, stream>>>(wout, woutbt, D_, D_, 0, 1.0f);

    gemm128_kernel<1, 1><<<dim3(NQKV_ / 128, ROWS_ / 128), 256, 0, stream>>>(
        xb, wqkvbt, qkb, ROWS_, D_, 2048, vtb);

    attn4_kernel<<<dim3(B_ * H_, 8), 256, 0, stream>>>(qkb, vtb, yb);

    gemm128_kernel<0, 0><<<dim3(D_ / 128, ROWS_ / 128), 256, 0, stream>>>(
        yb, woutbt, out, ROWS_, D_, D_, nullptr);
}

// Round 5
// 241.979 us; speedup vs baseline: 2.6448x; 1.0770x over previous
//
#include <hip/hip_runtime.h>
#include <hip/hip_bf16.h>
#include <stdint.h>

#define B_    4
#define T_    2048
#define D_    1024
#define H_    16
#define HD_   64
#define ROWS_ (B_ * T_)      // 8192
#define NQKV_ (3 * D_)       // 3072

typedef __attribute__((ext_vector_type(8))) short bf16x8;
typedef __attribute__((ext_vector_type(4))) float f32x4;

__device__ __forceinline__ unsigned short f2bf(float f) {
    union { float f; uint32_t u; } v; v.f = f;
    uint32_t u = v.u;
    return (unsigned short)((u + 0x7FFFu + ((u >> 16) & 1u)) >> 16);  // RNE
}

// RTZ pack of two floats to bf16x2 (lo = a). Used only for P (softmax
// self-normalizes: osum uses the same bf16 P, so the bias cancels).
__device__ __forceinline__ uint32_t pack2_rtz(float a, float b) {
    union { float f; uint32_t u; } x, y; x.f = a; y.f = b;
    return (x.u >> 16) | (y.u & 0xFFFF0000u);
}

__device__ __forceinline__ void glds16(const unsigned short* g, unsigned short* l) {
    __builtin_amdgcn_global_load_lds(
        (const __attribute__((address_space(1))) void*)g,
        (__attribute__((address_space(3))) void*)l, 16, 0, 0);
}

// ---------------- fp32 -> bf16 convert (plain) ----------------
__global__ void cvt_bf16_kernel(const float* __restrict__ in,
                                unsigned short* __restrict__ out, int n8) {
    int i = blockIdx.x * blockDim.x + threadIdx.x;
    if (i >= n8) return;
    float4 a = ((const float4*)in)[2 * i];
    float4 b = ((const float4*)in)[2 * i + 1];
    union { bf16x8 v; unsigned short s[8]; } o;
    o.s[0] = f2bf(a.x); o.s[1] = f2bf(a.y); o.s[2] = f2bf(a.z); o.s[3] = f2bf(a.w);
    o.s[4] = f2bf(b.x); o.s[5] = f2bf(b.y); o.s[6] = f2bf(b.z); o.s[7] = f2bf(b.w);
    ((bf16x8*)out)[i] = o.v;
}

// ---------------- fused weight transpose+convert ----------------
// fp32 [1024][N] -> bf16 [N][1024] for BOTH w_qkv (x<48, q-cols scaled) and
// w_out (x>=48). 64x64 tiles via LDS (stride 65 floats).
__global__ __launch_bounds__(256) void tcvt2_kernel(const float* __restrict__ wqkv,
                                                    const float* __restrict__ wout,
                                                    unsigned short* __restrict__ oqkv,
                                                    unsigned short* __restrict__ oout,
                                                    float scale) {
    __shared__ float tile[64 * 65];
    const int t = threadIdx.x;
    const bool second = blockIdx.x >= 48;
    const float* in = second ? wout : wqkv;
    unsigned short* out = second ? oout : oqkv;
    const int N = second ? 1024 : 3072;
    const int ncut = second ? 0 : 1024;
    const int n0 = (second ? (blockIdx.x - 48) : blockIdx.x) * 64;
    const int k0 = blockIdx.y * 64;
    const int K = 1024;
#pragma unroll
    for (int it = 0; it < 4; ++it) {
        int id = it * 256 + t;
        int r = id >> 4, c = (id & 15) * 4;
        float4 v = *(const float4*)&in[(size_t)(k0 + r) * N + n0 + c];
        tile[r * 65 + c + 0] = v.x; tile[r * 65 + c + 1] = v.y;
        tile[r * 65 + c + 2] = v.z; tile[r * 65 + c + 3] = v.w;
    }
    __syncthreads();
#pragma unroll
    for (int it = 0; it < 2; ++it) {
        int id = it * 256 + t;
        int n = id >> 3, kc = (id & 7) * 8;
        float sc = (n0 + n < ncut) ? scale : 1.0f;
        union { bf16x8 v; unsigned short s[8]; } o;
#pragma unroll
        for (int i = 0; i < 8; ++i) o.s[i] = f2bf(tile[(kc + i) * 65 + n] * sc);
        *(bf16x8*)&out[(size_t)(n0 + n) * K + k0 + kc] = o.v;
    }
}

// ---------------- GEMM: C[M,N] = A[M,K] * Bt[N,K]^T ----------------
// 128x128 tile, BK=64 (16 iters for K=1024 -> half the barrier drains),
// XOR-swizzled LDS 16B chunks (chunk' = chunk ^ (row&7)) so frag reads are
// 2-way-max on banks while glds dests stay lane-contiguous.
template<int OUT_BF16, int VSPLIT>
__global__ __launch_bounds__(256) void gemm128_kernel(
    const unsigned short* __restrict__ A,
    const unsigned short* __restrict__ Bt,
    void* __restrict__ Cp, int M, int K, int ldC,
    unsigned short* __restrict__ vt)
{
    __shared__ __align__(16) unsigned short As[128 * 64];
    __shared__ __align__(16) unsigned short Bs[128 * 64];

    const int t = threadIdx.x, w = t >> 6, lane = t & 63;
    const int wm = w >> 1, wn = w & 1;
    const int lm = lane & 15, lq = lane >> 4;
    const int m0 = blockIdx.y * 128, n0 = blockIdx.x * 128;

    f32x4 acc[4][4];
#pragma unroll
    for (int i = 0; i < 4; i++)
#pragma unroll
        for (int j = 0; j < 4; j++) acc[i][j] = (f32x4){0.f, 0.f, 0.f, 0.f};

    // staging: slot id s*256+t -> LDS 16B slot id (lane-contiguous);
    // global chunk = (id&7) ^ (row&7) of row id>>3 (XOR swizzle)
    const unsigned short* Ap[4];
    const unsigned short* Bp[4];
#pragma unroll
    for (int s = 0; s < 4; s++) {
        int id = s * 256 + t;
        int row = id >> 3, gch = (id & 7) ^ (row & 7);
        Ap[s] = A  + (size_t)(m0 + row) * K + gch * 8;
        Bp[s] = Bt + (size_t)(n0 + row) * K + gch * 8;
    }

    for (int k0 = 0; k0 < K; k0 += 64) {
        __syncthreads();
#pragma unroll
        for (int s = 0; s < 4; s++) glds16(Ap[s] + k0, &As[(s * 256 + t) * 8]);
#pragma unroll
        for (int s = 0; s < 4; s++) glds16(Bp[s] + k0, &Bs[(s * 256 + t) * 8]);
        __syncthreads();

#pragma unroll
        for (int kh = 0; kh < 2; kh++) {
            bf16x8 af[4], bfr[4];
#pragma unroll
            for (int mt = 0; mt < 4; mt++) {
                int row = wm * 64 + mt * 16 + lm;
                int sch = (kh * 4 + lq) ^ (lm & 7);
                af[mt] = *(const bf16x8*)&As[row * 64 + sch * 8];
            }
#pragma unroll
            for (int nt = 0; nt < 4; nt++) {
                int row = wn * 64 + nt * 16 + lm;
                int sch = (kh * 4 + lq) ^ (lm & 7);
                bfr[nt] = *(const bf16x8*)&Bs[row * 64 + sch * 8];
            }
#pragma unroll
            for (int mt = 0; mt < 4; mt++)
#pragma unroll
                for (int nt = 0; nt < 4; nt++)
                    acc[mt][nt] = __builtin_amdgcn_mfma_f32_16x16x32_bf16(
                        af[mt], bfr[nt], acc[mt][nt], 0, 0, 0);
        }
    }

    if (VSPLIT && n0 >= 2048) {
        // V columns -> vt[(b*16+h)*64 + d][t]; r=0..3 contiguous in tt -> b64
#pragma unroll
        for (int mt = 0; mt < 4; mt++)
#pragma unroll
            for (int nt = 0; nt < 4; nt++) {
                int row0 = m0 + wm * 64 + mt * 16 + lq * 4;
                int col  = n0 + wn * 64 + nt * 16 + lm - 2048;
                int bb = row0 >> 11, tt = row0 & 2047;
                size_t vi = ((size_t)((bb * 16 + (col >> 6)) * 64 + (col & 63))) * 2048 + tt;
                uint2 pk;
                pk.x = (uint32_t)f2bf(acc[mt][nt][0]) | ((uint32_t)f2bf(acc[mt][nt][1]) << 16);
                pk.y = (uint32_t)f2bf(acc[mt][nt][2]) | ((uint32_t)f2bf(acc[mt][nt][3]) << 16);
                *(uint2*)&vt[vi] = pk;
            }
        return;
    }
#pragma unroll
    for (int mt = 0; mt < 4; mt++)
#pragma unroll
        for (int nt = 0; nt < 4; nt++)
#pragma unroll
            for (int r = 0; r < 4; r++) {
                int row = m0 + wm * 64 + mt * 16 + lq * 4 + r;
                int col = n0 + wn * 64 + nt * 16 + lm;
                if (OUT_BF16)
                    ((unsigned short*)Cp)[(size_t)row * ldC + col] = f2bf(acc[mt][nt][r]);
                else
                    ((float*)Cp)[(size_t)row * ldC + col] = acc[mt][nt][r];
            }
}

// ---------------- fused causal flash attention v4 ----------------
// Max-free softmax + S^T operand-swap (packed b64 P stores) + register
// prefetch of next K/V tile. Block = (b,h) x qt pair {15-i, i}.
__global__ __launch_bounds__(256) void attn4_kernel(
    const unsigned short* __restrict__ qk,
    const unsigned short* __restrict__ vt,
    unsigned short* __restrict__ y)
{
    __shared__ __align__(16) unsigned short Ks[64 * 72];
    __shared__ __align__(16) unsigned short Vs[64 * 72];
    __shared__ __align__(16) unsigned short Ps[4][32 * 72];

    const int bh = blockIdx.x, pair = blockIdx.y;
    const int b = bh >> 4, h = bh & 15;
    const int t = threadIdx.x, w = t >> 6, lane = t & 63;
    const int lm = lane & 15, lq = lane >> 4;
    unsigned short* psw = Ps[w];

    const int r0 = t >> 3,           c0 = (t & 7) * 8;
    const int r1 = (256 + t) >> 3,   c1 = (t & 7) * 8;
    const unsigned short* kgb = qk + (size_t)(b * T_) * 2048 + D_ + h * HD_;
    const unsigned short* vgb = vt + (size_t)(bh * 64) * 2048;

    const bf16x8 onesf = {0x3F80, 0x3F80, 0x3F80, 0x3F80,
                          0x3F80, 0x3F80, 0x3F80, 0x3F80};  // bf16 1.0 x8

    for (int which = 0; which < 2; ++which) {
        const int qt = which ? pair : (15 - pair);   // big tile first
        const int q0 = qt * 128, qw0 = q0 + w * 32;

        bf16x8 qf[2][2];
#pragma unroll
        for (int mt = 0; mt < 2; mt++)
#pragma unroll
            for (int kk = 0; kk < 2; kk++)
                qf[mt][kk] = *(const bf16x8*)
                    &qk[(size_t)(b * T_ + qw0 + mt * 16 + lm) * 2048 + h * HD_ + kk * 32 + lq * 8];

        f32x4 o[2][4], osum[2];
#pragma unroll
        for (int mt = 0; mt < 2; mt++) {
            osum[mt] = (f32x4){0.f, 0.f, 0.f, 0.f};
#pragma unroll
            for (int dt = 0; dt < 4; dt++) o[mt][dt] = (f32x4){0.f, 0.f, 0.f, 0.f};
        }

        const int kend = q0 + 128;

        bf16x8 ka = *(const bf16x8*)&kgb[(size_t)(0 + r0) * 2048 + c0];
        bf16x8 kb = *(const bf16x8*)&kgb[(size_t)(0 + r1) * 2048 + c1];
        bf16x8 va = *(const bf16x8*)&vgb[(size_t)r0 * 2048 + 0 + c0];
        bf16x8 vb = *(const bf16x8*)&vgb[(size_t)r1 * 2048 + 0 + c1];

        for (int kt = 0; kt < kend; kt += 64) {
            __syncthreads();
            *(bf16x8*)&Ks[r0 * 72 + c0] = ka;
            *(bf16x8*)&Ks[r1 * 72 + c1] = kb;
            *(bf16x8*)&Vs[r0 * 72 + c0] = va;
            *(bf16x8*)&Vs[r1 * 72 + c1] = vb;
            int ktn = (kt + 64 < kend) ? kt + 64 : kt;
            ka = *(const bf16x8*)&kgb[(size_t)(ktn + r0) * 2048 + c0];
            kb = *(const bf16x8*)&kgb[(size_t)(ktn + r1) * 2048 + c1];
            va = *(const bf16x8*)&vgb[(size_t)r0 * 2048 + ktn + c0];
            vb = *(const bf16x8*)&vgb[(size_t)r1 * 2048 + ktn + c1];
            __syncthreads();
            if (kt >= qw0 + 32) continue;

            // S^T = K Q^T: lane holds (row=key=lq*4+r, col=query=lm)
            f32x4 st[4][2];
#pragma unroll
            for (int nt = 0; nt < 4; nt++)
#pragma unroll
                for (int mt = 0; mt < 2; mt++) st[nt][mt] = (f32x4){0.f, 0.f, 0.f, 0.f};
#pragma unroll
            for (int nt = 0; nt < 4; nt++)
#pragma unroll
                for (int kk = 0; kk < 2; kk++) {
                    bf16x8 kf = *(const bf16x8*)&Ks[(nt * 16 + lm) * 72 + kk * 32 + lq * 8];
#pragma unroll
                    for (int mt = 0; mt < 2; mt++)
                        st[nt][mt] = __builtin_amdgcn_mfma_f32_16x16x32_bf16(
                            kf, qf[mt][kk], st[nt][mt], 0, 0, 0);
                }

            const bool diag = (kt + 64 > qw0);
#pragma unroll
            for (int mt = 0; mt < 2; mt++) {
                const int qi = qw0 + mt * 16 + lm;
#pragma unroll
                for (int nt = 0; nt < 4; nt++) {
                    float p[4];
                    if (diag) {
                        const int kj0 = kt + nt * 16 + lq * 4;
#pragma unroll
                        for (int r = 0; r < 4; r++)
                            p[r] = (kj0 + r <= qi)
                                 ? __builtin_amdgcn_exp2f(st[nt][mt][r]) : 0.f;
                    } else {
#pragma unroll
                        for (int r = 0; r < 4; r++)
                            p[r] = __builtin_amdgcn_exp2f(st[nt][mt][r]);
                    }
                    uint2 pk;
                    pk.x = pack2_rtz(p[0], p[1]);
                    pk.y = pack2_rtz(p[2], p[3]);
                    *(uint2*)&psw[(mt * 16 + lm) * 72 + nt * 16 + lq * 4] = pk;
                }
            }

#pragma unroll
            for (int kk = 0; kk < 2; kk++) {
                bf16x8 pf0 = *(const bf16x8*)&psw[(lm) * 72 + kk * 32 + lq * 8];
                bf16x8 pf1 = *(const bf16x8*)&psw[(16 + lm) * 72 + kk * 32 + lq * 8];
                osum[0] = __builtin_amdgcn_mfma_f32_16x16x32_bf16(pf0, onesf, osum[0], 0, 0, 0);
                osum[1] = __builtin_amdgcn_mfma_f32_16x16x32_bf16(pf1, onesf, osum[1], 0, 0, 0);
#pragma unroll
                for (int dt = 0; dt < 4; dt++) {
                    bf16x8 vf = *(const bf16x8*)&Vs[(dt * 16 + lm) * 72 + kk * 32 + lq * 8];
                    o[0][dt] = __builtin_amdgcn_mfma_f32_16x16x32_bf16(pf0, vf, o[0][dt], 0, 0, 0);
                    o[1][dt] = __builtin_amdgcn_mfma_f32_16x16x32_bf16(pf1, vf, o[1][dt], 0, 0, 0);
                }
            }
        }

#pragma unroll
        for (int mt = 0; mt < 2; mt++)
#pragma unroll
            for (int r = 0; r < 4; r++) {
                float rli = 1.f / osum[mt][r];
#pragma unroll
                for (int dt = 0; dt < 4; dt++)
                    y[(size_t)(b * T_ + qw0 + mt * 16 + lq * 4 + r) * D_ + h * HD_ + dt * 16 + lm]
                        = f2bf(o[mt][dt][r] * rli);
            }
    }
}

// ---------------- launch ----------------
extern "C" void kernel_launch(void* const* d_in, const int* in_sizes, int n_in,
                              void* d_out, int out_size, void* d_ws, size_t ws_size,
                              hipStream_t stream) {
    const float* x    = (const float*)d_in[0];
    const float* wqkv = (const float*)d_in[1];
    const float* wout = (const float*)d_in[2];
    float* out = (float*)d_out;

    char* ws = (char*)d_ws;
    unsigned short* xb     = (unsigned short*)ws; ws += (size_t)ROWS_ * D_ * 2;
    unsigned short* wqkvbt = (unsigned short*)ws; ws += (size_t)D_ * NQKV_ * 2;
    unsigned short* woutbt = (unsigned short*)ws; ws += (size_t)D_ * D_ * 2;
    unsigned short* qkb    = (unsigned short*)ws; ws += (size_t)ROWS_ * 2048 * 2;
    unsigned short* vtb    = (unsigned short*)ws; ws += (size_t)ROWS_ * D_ * 2;
    unsigned short* yb     = (unsigned short*)ws;

    const float SC = 0.18033688011112042f;  // 0.125 * log2(e): softmax in exp2 domain

    cvt_bf16_kernel<<<ROWS_ * D_ / 8 / 256, 256, 0, stream>>>(x, xb, ROWS_ * D_ / 8);
    tcvt2_kernel<<<dim3(64, 16), 256, 0, stream>>>(wqkv, wout, wqkvbt, woutbt, SC);

    gemm128_kernel<1, 1><<<dim3(NQKV_ / 128, ROWS_ / 128), 256, 0, stream>>>(
        xb, wqkvbt, qkb, ROWS_, D_, 2048, vtb);

    attn4_kernel<<<dim3(B_ * H_, 8), 256, 0, stream>>>(qkb, vtb, yb);

    gemm128_kernel<0, 0><<<dim3(D_ / 128, ROWS_ / 128), 256, 0, stream>>>(
        yb, woutbt, out, ROWS_, D_, D_, nullptr);
}